// Round 6
// baseline (112.404 us; speedup 1.0000x reference)
//
#include <hip/hip_runtime.h>

#define RES 128
#define FEAT 8
#define NFINE 4096            // 16^3 fine buckets, each 8^3 cells
#define NCOARSE 64            // 4^3 coarse buckets, each 32^3 cells
#define CAP 32768             // fixed capacity per coarse region in sorted1
#define W1 2048               // pass-1 window (pts per block) == 256 threads * 8 pts
#define W2 2048               // pass-2 window
#define WPR (CAP / W2)        // windows per coarse region = 16

// slab: 9^3 = 729 cells * 32 B = 1458 16-B chunks; XOR swizzle s = t ^ ((t>>3)&7)
// maps [0,1458) into [0,1464) -> allocate 1464 chunks per buffer.
#define NCHUNK 1458
#define NSLOT  1464

#define GLOBAL_AS __attribute__((address_space(1)))
#define LDS_AS __attribute__((address_space(3)))

__device__ __forceinline__ void cell_of(float px, float py, float pz,
                                        int& ix, int& iy, int& iz,
                                        float& fx, float& fy, float& fz) {
    // exact reference op order: ((p + 1) * 0.5) * (res - 1)
    float x = (px + 1.0f) * 0.5f * (float)(RES - 1);
    float y = (py + 1.0f) * 0.5f * (float)(RES - 1);
    float z = (pz + 1.0f) * 0.5f * (float)(RES - 1);
    float fx0 = fminf(fmaxf(floorf(x), 0.0f), (float)(RES - 2));
    float fy0 = fminf(fmaxf(floorf(y), 0.0f), (float)(RES - 2));
    float fz0 = fminf(fmaxf(floorf(z), 0.0f), (float)(RES - 2));
    ix = (int)fx0; iy = (int)fy0; iz = (int)fz0;
    fx = x - fx0; fy = y - fy0; fz = z - fz0;
}

// fine id grouped so that one coarse bucket = 64 consecutive fine ids
__device__ __forceinline__ int fine_of(int ix, int iy, int iz) {
    int c = ((ix >> 5) << 4) | ((iy >> 5) << 2) | (iz >> 5);
    int s = (((ix >> 3) & 3) << 4) | (((iy >> 3) & 3) << 2) | ((iz >> 3) & 3);
    return (c << 6) | s;
}

__device__ __forceinline__ void bucket_origin(int fine, int& ox, int& oy, int& oz) {
    int c = fine >> 6, s = fine & 63;
    ox = (((((c >> 4) & 3) << 2) | ((s >> 4) & 3))) << 3;
    oy = (((((c >> 2) & 3) << 2) | ((s >> 2) & 3))) << 3;
    oz = ((((c & 3) << 2) | (s & 3))) << 3;
}

__global__ void init_kernel(unsigned int* hist, unsigned int* cursor) {
    int i = blockIdx.x * blockDim.x + threadIdx.x;
    if (i < NFINE) hist[i] = 0u;
    if (i < NCOARSE) cursor[i] = (unsigned int)(i * CAP);
}

// vectorized: each thread handles 8 consecutive points via 6 float4 loads
__global__ __launch_bounds__(256) void hist_kernel(const float* __restrict__ pts,
                                                   unsigned int* __restrict__ hist,
                                                   int npts) {
    __shared__ unsigned int lh[NFINE];
    for (int b = threadIdx.x; b < NFINE; b += 256) lh[b] = 0u;
    __syncthreads();
    const float4* pts4 = reinterpret_cast<const float4*>(pts);
    int ngrp = npts >> 3;  // groups of 8 points (24 floats = 6 float4)
    int stride = gridDim.x * 256;
    for (int g = blockIdx.x * 256 + threadIdx.x; g < ngrp; g += stride) {
        const float4* bp = pts4 + (size_t)g * 6;
        float4 v0 = bp[0], v1 = bp[1], v2 = bp[2], v3 = bp[3], v4 = bp[4], v5 = bp[5];
        float P[24] = {v0.x, v0.y, v0.z, v0.w, v1.x, v1.y, v1.z, v1.w,
                       v2.x, v2.y, v2.z, v2.w, v3.x, v3.y, v3.z, v3.w,
                       v4.x, v4.y, v4.z, v4.w, v5.x, v5.y, v5.z, v5.w};
#pragma unroll
        for (int k = 0; k < 8; ++k) {
            int ix, iy, iz; float fx, fy, fz;
            cell_of(P[3 * k], P[3 * k + 1], P[3 * k + 2], ix, iy, iz, fx, fy, fz);
            atomicAdd(&lh[fine_of(ix, iy, iz)], 1u);
        }
    }
    // scalar tail
    if (blockIdx.x == 0) {
        for (int i = (ngrp << 3) + threadIdx.x; i < npts; i += 256) {
            int ix, iy, iz; float fx, fy, fz;
            cell_of(pts[3 * i], pts[3 * i + 1], pts[3 * i + 2], ix, iy, iz, fx, fy, fz);
            atomicAdd(&lh[fine_of(ix, iy, iz)], 1u);
        }
    }
    __syncthreads();
    for (int b = threadIdx.x; b < NFINE; b += 256) {
        unsigned int v = lh[b];
        if (v) atomicAdd(&hist[b], v);
    }
}

// single block, 1024 threads: exclusive scan of 4096 bins -> two copies + total
__global__ __launch_bounds__(1024) void scan_kernel(const unsigned int* __restrict__ hist,
                                                    unsigned int* __restrict__ offs_mut,
                                                    unsigned int* __restrict__ offs_ro,
                                                    int npts) {
    __shared__ unsigned int tot[1024];
    int t = threadIdx.x;
    uint4 h = reinterpret_cast<const uint4*>(hist)[t];
    unsigned int s0 = h.x;
    unsigned int s1 = s0 + h.y;
    unsigned int s2 = s1 + h.z;
    unsigned int s3 = s2 + h.w;
    tot[t] = s3;
    __syncthreads();
    for (int off = 1; off < 1024; off <<= 1) {
        unsigned int v = (t >= off) ? tot[t - off] : 0u;
        __syncthreads();
        tot[t] += v;
        __syncthreads();
    }
    unsigned int excl = (t == 0) ? 0u : tot[t - 1];
    uint4 o = make_uint4(excl, excl + s0, excl + s1, excl + s2);
    reinterpret_cast<uint4*>(offs_mut)[t] = o;
    reinterpret_cast<uint4*>(offs_ro)[t] = o;
    if (t == 0) offs_ro[NFINE] = (unsigned int)npts;
}

// pass 1: raw pts -> sorted1 (d_out scratch), coarse-bucketed, LDS-reordered runs.
__global__ __launch_bounds__(256) void pass1_kernel(const float* __restrict__ pts,
                                                    unsigned int* __restrict__ cursor,
                                                    float4* __restrict__ sorted1,
                                                    int npts) {
    __shared__ unsigned int cnt[NCOARSE], pfx[NCOARSE], base[NCOARSE];
    __shared__ float4 buf[W1];
    __shared__ unsigned char binof[W1];
    int tid = threadIdx.x;
    int blockStart = blockIdx.x * W1;
    int valid = min(W1, npts - blockStart);
    if (valid <= 0) return;
    if (tid < NCOARSE) cnt[tid] = 0u;
    __syncthreads();

    float ppx[8], ppy[8], ppz[8];
    int pc[8], pr[8];
    int jb = tid * 8;  // this thread's first point within the window
    if (jb + 7 < valid) {
        const float4* bp = reinterpret_cast<const float4*>(pts) +
                           ((size_t)blockStart * 3) / 4 + (size_t)tid * 6;
        float4 v0 = bp[0], v1 = bp[1], v2 = bp[2], v3 = bp[3], v4 = bp[4], v5 = bp[5];
        float P[24] = {v0.x, v0.y, v0.z, v0.w, v1.x, v1.y, v1.z, v1.w,
                       v2.x, v2.y, v2.z, v2.w, v3.x, v3.y, v3.z, v3.w,
                       v4.x, v4.y, v4.z, v4.w, v5.x, v5.y, v5.z, v5.w};
#pragma unroll
        for (int k = 0; k < 8; ++k) {
            ppx[k] = P[3 * k]; ppy[k] = P[3 * k + 1]; ppz[k] = P[3 * k + 2];
            int ix, iy, iz; float fx, fy, fz;
            cell_of(ppx[k], ppy[k], ppz[k], ix, iy, iz, fx, fy, fz);
            int c = fine_of(ix, iy, iz) >> 6;
            pr[k] = (int)atomicAdd(&cnt[c], 1u);
            pc[k] = c;
        }
    } else {
#pragma unroll
        for (int k = 0; k < 8; ++k) {
            int j = jb + k;
            pc[k] = -1;
            if (j < valid) {
                int i = blockStart + j;
                float px = pts[3 * i], py = pts[3 * i + 1], pz = pts[3 * i + 2];
                int ix, iy, iz; float fx, fy, fz;
                cell_of(px, py, pz, ix, iy, iz, fx, fy, fz);
                int c = fine_of(ix, iy, iz) >> 6;
                pr[k] = (int)atomicAdd(&cnt[c], 1u);
                pc[k] = c;
                ppx[k] = px; ppy[k] = py; ppz[k] = pz;
            }
        }
    }
    bool allv = (jb + 7 < valid);
    __syncthreads();
    if (tid == 0) {
        unsigned int s = 0;
        for (int b = 0; b < NCOARSE; ++b) { pfx[b] = s; s += cnt[b]; }
    }
    __syncthreads();
    if (tid < NCOARSE && cnt[tid] > 0)
        base[tid] = atomicAdd(&cursor[tid], cnt[tid]);
    __syncthreads();
#pragma unroll
    for (int k = 0; k < 8; ++k) {
        if (allv || (jb + k < valid && pc[k] >= 0)) {
            int i = blockStart + jb + k;
            unsigned int slot = pfx[pc[k]] + (unsigned int)pr[k];
            buf[slot] = make_float4(ppx[k], ppy[k], ppz[k], __int_as_float(i));
            binof[slot] = (unsigned char)pc[k];
        }
    }
    __syncthreads();
#pragma unroll
    for (int k = 0; k < 8; ++k) {
        int slot = k * 256 + tid;
        if (slot < valid) {
            int b = binof[slot];
            unsigned int pos = base[b] + (unsigned int)slot - pfx[b];
            sorted1[pos] = buf[slot];
        }
    }
}

// pass 2: sorted1 coarse regions -> sorted2 fine-bucketed (ws), LDS-reordered runs
__global__ __launch_bounds__(256) void pass2_kernel(const float4* __restrict__ sorted1,
                                                    const unsigned int* __restrict__ cursor,
                                                    unsigned int* __restrict__ offs_mut,
                                                    float4* __restrict__ sorted2) {
    int c = blockIdx.x / WPR;
    int w = blockIdx.x % WPR;
    unsigned int count = cursor[c] - (unsigned int)(c * CAP);
    if (count > CAP) count = CAP;  // safety clamp
    int valid = min(W2, (int)count - w * W2);
    if (valid <= 0) return;
    __shared__ unsigned int cnt[64], pfx[64], base[64];
    __shared__ float4 buf[W2];
    __shared__ unsigned char binof[W2];
    int tid = threadIdx.x;
    int start = c * CAP + w * W2;
    if (tid < 64) cnt[tid] = 0u;
    __syncthreads();

    float4 pq[8];
    int ps[8], pr[8];
#pragma unroll
    for (int k = 0; k < 8; ++k) {
        int j = k * 256 + tid;
        ps[k] = -1;
        if (j < valid) {
            float4 q = sorted1[start + j];
            int ix, iy, iz; float fx, fy, fz;
            cell_of(q.x, q.y, q.z, ix, iy, iz, fx, fy, fz);
            int s = (((ix >> 3) & 3) << 4) | (((iy >> 3) & 3) << 2) | ((iz >> 3) & 3);
            pr[k] = (int)atomicAdd(&cnt[s], 1u);
            ps[k] = s;
            pq[k] = q;
        }
    }
    __syncthreads();
    if (tid == 0) {
        unsigned int s = 0;
        for (int b = 0; b < 64; ++b) { pfx[b] = s; s += cnt[b]; }
    }
    __syncthreads();
    if (tid < 64 && cnt[tid] > 0)
        base[tid] = atomicAdd(&offs_mut[c * 64 + tid], cnt[tid]);
    __syncthreads();
#pragma unroll
    for (int k = 0; k < 8; ++k) {
        if (ps[k] >= 0) {
            unsigned int slot = pfx[ps[k]] + (unsigned int)pr[k];
            buf[slot] = pq[k];
            binof[slot] = (unsigned char)ps[k];
        }
    }
    __syncthreads();
#pragma unroll
    for (int k = 0; k < 8; ++k) {
        int slot = k * 256 + tid;
        if (slot < valid) {
            int b = binof[slot];
            unsigned int pos = base[b] + (unsigned int)slot - pfx[b];
            sorted2[pos] = buf[slot];
        }
    }
}

// ---- persistent trilerp: 512 blocks x 512 threads, 8 buckets/block, dbuf slab ----

// stage one bucket's 9^3 slab into buf via global_load_lds.
// LDS dest is linear in slot; the chunk-XOR swizzle s=t^((t>>3)&7) (involution)
// is applied by pre-swizzling the GLOBAL source chunk (m173 pattern).
__device__ __forceinline__ void stage_bucket(const float* __restrict__ features,
                                             float* __restrict__ buf,
                                             int fine, int tid) {
    int ox, oy, oz;
    bucket_origin(fine, ox, oy, oz);
#pragma unroll
    for (int k = 0; k < 3; ++k) {
        int slot = k * 512 + tid;
        if (slot < NSLOT) {
            int t2 = slot ^ ((slot >> 3) & 7);   // involution: chunk held at this slot
            if (t2 >= NCHUNK) t2 = 0;            // dummy (slot never read)
            int cell = t2 >> 1, half = t2 & 1;
            int lx = cell / 81, rr = cell - lx * 81, ly = rr / 9, lz = rr - ly * 9;
            int gx = min(ox + lx, RES - 1);
            int gy = min(oy + ly, RES - 1);
            int gz = min(oz + lz, RES - 1);
            const float* src =
                features + (size_t)((((gx << 7) | gy) << 7) | gz) * FEAT + half * 4;
            int base_slot = k * 512 + (tid & ~63);  // wave-uniform LDS base
            __builtin_amdgcn_global_load_lds((const GLOBAL_AS void*)src,
                                             (LDS_AS void*)(buf + (base_slot << 2)),
                                             16, 0, 0);
        }
    }
}

__device__ __forceinline__ void lerp_point_swz(const float* __restrict__ buf, float4 q,
                                               int ox, int oy, int oz,
                                               float* __restrict__ out) {
    int oi = __float_as_int(q.w);
    int ix, iy, iz; float fx, fy, fz;
    cell_of(q.x, q.y, q.z, ix, iy, iz, fx, fy, fz);
    int lx = ix - ox, ly = iy - oy, lz = iz - oz;
    int c000 = (lx * 9 + ly) * 9 + lz;

    float wx[2] = {1.0f - fx, fx};
    float wy[2] = {1.0f - fy, fy};
    float wz[2] = {1.0f - fz, fz};

    float acc[FEAT];
#pragma unroll
    for (int k = 0; k < FEAT; ++k) acc[k] = 0.0f;

#pragma unroll
    for (int dx = 0; dx < 2; ++dx) {
#pragma unroll
        for (int dy = 0; dy < 2; ++dy) {
#pragma unroll
            for (int dz = 0; dz < 2; ++dz) {
                float w = wx[dx] * wy[dy] * wz[dz];
                int ci = c000 + dx * 81 + dy * 9 + dz;
                int t0 = ci << 1, t1 = t0 + 1;
                int s0 = t0 ^ ((t0 >> 3) & 7);
                int s1 = t1 ^ ((t1 >> 3) & 7);
                float4 a = *reinterpret_cast<const float4*>(buf + (s0 << 2));
                float4 b = *reinterpret_cast<const float4*>(buf + (s1 << 2));
                acc[0] += w * a.x; acc[1] += w * a.y;
                acc[2] += w * a.z; acc[3] += w * a.w;
                acc[4] += w * b.x; acc[5] += w * b.y;
                acc[6] += w * b.z; acc[7] += w * b.w;
            }
        }
    }
    float4* op = reinterpret_cast<float4*>(out + (size_t)oi * FEAT);
    op[0] = make_float4(acc[0], acc[1], acc[2], acc[3]);
    op[1] = make_float4(acc[4], acc[5], acc[6], acc[7]);
}

__global__ __launch_bounds__(512) void trilerp_persist(const float4* __restrict__ sorted2,
                                                       const float* __restrict__ features,
                                                       const unsigned int* __restrict__ offs_ro,
                                                       float* __restrict__ out) {
    __shared__ __align__(16) float slab[2][NSLOT * 4];  // 2 x 23424 B
    int tid = threadIdx.x;
    // XCD x (= bid%8) owns fine ids [x*512, (x+1)*512); block j within XCD owns
    // 8 consecutive fine ids (a z-column of sub-buckets -> overlapping slabs).
    int x = blockIdx.x & 7, j = blockIdx.x >> 3;
    int fineBase = x * 512 + j * 8;

    // prologue: stage + point-prefetch bucket 0
    int f0 = fineBase;
    int start_c = (int)offs_ro[f0], end_c = (int)offs_ro[f0 + 1];
    stage_bucket(features, slab[0], f0, tid);
    int n0 = start_c + tid, n1 = n0 + 512;
    bool v0c = n0 < end_c, v1c = n1 < end_c;
    float4 p0c = {}, p1c = {};
    if (v0c) p0c = sorted2[n0];
    if (v1c) p1c = sorted2[n1];
    __syncthreads();  // vmcnt(0) drain: slab[0] + prefetch ready

    for (int t = 0; t < 8; ++t) {
        int cur = t & 1;
        int fine = fineBase + t;
        int ox, oy, oz;
        bucket_origin(fine, ox, oy, oz);

        // issue next bucket's staging + point prefetch BEFORE compute;
        // the end-of-iter barrier's vmcnt(0) is the only wait they ever see.
        int start_n = 0, end_n = 0;
        bool v0n = false, v1n = false;
        float4 p0n = {}, p1n = {};
        if (t < 7) {
            int fn = fine + 1;
            stage_bucket(features, slab[cur ^ 1], fn, tid);
            start_n = (int)offs_ro[fn];
            end_n = (int)offs_ro[fn + 1];
            int m0 = start_n + tid, m1 = m0 + 512;
            v0n = m0 < end_n; v1n = m1 < end_n;
            if (v0n) p0n = sorted2[m0];
            if (v1n) p1n = sorted2[m1];
        }

        const float* buf = slab[cur];
        if (v0c) lerp_point_swz(buf, p0c, ox, oy, oz, out);
        if (v1c) lerp_point_swz(buf, p1c, ox, oy, oz, out);
        // rare tail: bucket > 1024 pts (>24 sigma; effectively never)
        for (int p = start_c + 1024 + tid; p < end_c; p += 512)
            lerp_point_swz(buf, sorted2[p], ox, oy, oz, out);

        __syncthreads();  // all waves done reading slab[cur]; slab[cur^1] staged

        start_c = start_n; end_c = end_n;
        v0c = v0n; v1c = v1n; p0c = p0n; p1c = p1n;
    }
}

// round-1 fallback (used only if ws_size is too small)
__global__ __launch_bounds__(256) void trilerp_kernel(const float* __restrict__ pts,
                                                      const float* __restrict__ features,
                                                      float* __restrict__ out,
                                                      int npts) {
    int i = blockIdx.x * blockDim.x + threadIdx.x;
    if (i >= npts) return;
    int ix, iy, iz; float fx, fy, fz;
    cell_of(pts[3 * i], pts[3 * i + 1], pts[3 * i + 2], ix, iy, iz, fx, fy, fz);
    float wx[2] = {1.0f - fx, fx};
    float wy[2] = {1.0f - fy, fy};
    float wz[2] = {1.0f - fz, fz};
    float acc[FEAT];
#pragma unroll
    for (int k = 0; k < FEAT; ++k) acc[k] = 0.0f;
    int base = (ix * RES + iy) * RES + iz;
#pragma unroll
    for (int dx = 0; dx < 2; ++dx)
#pragma unroll
        for (int dy = 0; dy < 2; ++dy)
#pragma unroll
            for (int dz = 0; dz < 2; ++dz) {
                int idxc = base + dx * (RES * RES) + dy * RES + dz;
                float w = wx[dx] * wy[dy] * wz[dz];
                const float4* fp =
                    reinterpret_cast<const float4*>(features + (size_t)idxc * FEAT);
                float4 a = fp[0];
                float4 b = fp[1];
                acc[0] += w * a.x; acc[1] += w * a.y;
                acc[2] += w * a.z; acc[3] += w * a.w;
                acc[4] += w * b.x; acc[5] += w * b.y;
                acc[6] += w * b.z; acc[7] += w * b.w;
            }
    float4* op = reinterpret_cast<float4*>(out + (size_t)i * FEAT);
    op[0] = make_float4(acc[0], acc[1], acc[2], acc[3]);
    op[1] = make_float4(acc[4], acc[5], acc[6], acc[7]);
}

extern "C" void kernel_launch(void* const* d_in, const int* in_sizes, int n_in,
                              void* d_out, int out_size, void* d_ws, size_t ws_size,
                              hipStream_t stream) {
    const float* pts = (const float*)d_in[0];
    const float* features = (const float*)d_in[1];
    float* out = (float*)d_out;
    int npts = in_sizes[0] / 3;

    size_t need = (size_t)npts * sizeof(float4)
                + (size_t)(NFINE + NFINE + NFINE + 1 + NCOARSE) * 4u + 256u;
    bool out_big_enough = (size_t)out_size * 4u >= (size_t)NCOARSE * CAP * sizeof(float4);
    if (ws_size < need || !out_big_enough || npts > NCOARSE * CAP) {
        int block = 256;
        int grid = (npts + block - 1) / block;
        trilerp_kernel<<<grid, block, 0, stream>>>(pts, features, out, npts);
        return;
    }

    char* w = (char*)d_ws;
    float4* sorted2 = (float4*)w;              w += (size_t)npts * sizeof(float4);
    unsigned int* hist = (unsigned int*)w;     w += NFINE * 4u;
    unsigned int* offs_mut = (unsigned int*)w; w += NFINE * 4u;
    unsigned int* offs_ro = (unsigned int*)w;  w += (NFINE + 1) * 4u;
    unsigned int* cursor = (unsigned int*)w;

    float4* sorted1 = (float4*)d_out;  // first 32 MiB of d_out as scratch;
                                       // dead before trilerp_persist overwrites all of out

    init_kernel<<<(NFINE + 255) / 256, 256, 0, stream>>>(hist, cursor);
    hist_kernel<<<256, 256, 0, stream>>>(pts, hist, npts);
    scan_kernel<<<1, 1024, 0, stream>>>(hist, offs_mut, offs_ro, npts);
    pass1_kernel<<<(npts + W1 - 1) / W1, 256, 0, stream>>>(pts, cursor, sorted1, npts);
    pass2_kernel<<<NCOARSE * WPR, 256, 0, stream>>>(sorted1, cursor, offs_mut, sorted2);
    trilerp_persist<<<512, 512, 0, stream>>>(sorted2, features, offs_ro, out);
}